// Round 17
// baseline (208.232 us; speedup 1.0000x reference)
//
#include <hip/hip_runtime.h>
#include <math.h>

#define D_MODEL 1024
#define NUM_HEADS 16
#define D_HEAD 64
#define SEQ 2048
#define BATCH 2

typedef __attribute__((ext_vector_type(8))) short short8;
typedef __attribute__((ext_vector_type(4))) float float4v;
typedef __attribute__((ext_vector_type(2))) unsigned int uint2v;
typedef __attribute__((ext_vector_type(4))) unsigned int uint4v;

__device__ __forceinline__ short f2bf(float f) {
    unsigned u = __float_as_uint(f);
    u += 0x7FFFu + ((u >> 16) & 1u);
    return (short)(u >> 16);
}

__device__ __forceinline__ float fexp2(float x) {
    return __builtin_amdgcn_exp2f(x);      // raw v_exp_f32 (exp2 domain)
}

// 8 fp32 -> 8 bf16 (RNE, same as f2bf) packed into 4 dwords via cvt_pk.
__device__ __forceinline__ uint4v cvt8(float4 lo, float4 hi) {
    uint4v r;
    asm("v_cvt_pk_bf16_f32 %0, %1, %2" : "=v"(r[0]) : "v"(lo.x), "v"(lo.y));
    asm("v_cvt_pk_bf16_f32 %0, %1, %2" : "=v"(r[1]) : "v"(lo.z), "v"(lo.w));
    asm("v_cvt_pk_bf16_f32 %0, %1, %2" : "=v"(r[2]) : "v"(hi.x), "v"(hi.y));
    asm("v_cvt_pk_bf16_f32 %0, %1, %2" : "=v"(r[3]) : "v"(hi.z), "v"(hi.w));
    return r;
}

// Raw-instruction sincos of (rev revolutions): v_fract + v_sin/v_cos.
// NOT libm (sincosf codegen poisons MFMA kernels); rev>256 needs the fract.
__device__ __forceinline__ void sincos_rev(float rev, float* sn, float* cs) {
    float fr;
    asm("v_fract_f32 %0, %1" : "=v"(fr) : "v"(rev));
    asm("v_sin_f32 %0, %1" : "=v"(*sn) : "v"(fr));
    asm("v_cos_f32 %0, %1" : "=v"(*cs) : "v"(fr));
}

// ---------------------------------------------------------------------------
// R25 qkv GEMM core: identical structure to the 5-attack-surviving reg-staged
// core (2-deep register pipeline + XOR bank swizzle), but sources are FP32
// (x, W) converted in-flight with v_cvt_pk_bf16_f32 at the LDS-write stage.
// This deletes the cvt kernel (one launch + ~9us) at the cost of 16 cvt_pk
// per wave-kstep and doubled staging bytes (L3-resident sources).
// ---------------------------------------------------------------------------
__device__ __forceinline__ void gemm_core_f32(
    const float* __restrict__ a, const float* __restrict__ b,
    short* smem, int m0, int n0, float4v acc[4][4])
{
    const int tid = threadIdx.x;
    const int lane = tid & 63;
    const int l15 = lane & 15, quad = lane >> 4;
    const int wave = tid >> 6;
    const int mw = (wave & 1) * 64, nw = (wave >> 1) * 64;
    const int srow = tid >> 2;
    const int scol = (tid & 3) * 8;
    const int ssw = (((tid & 3) ^ ((srow >> 1) & 3))) * 8;
    const int xsw = (l15 >> 1) & 3;

    const float* ag = a + (size_t)(m0 + srow) * D_MODEL + scol;
    const float* bg = b + (size_t)(n0 + srow) * D_MODEL + scol;

    short* bufA[2] = { smem,        smem + 8192 };
    short* bufB[2] = { smem + 4096, smem + 12288 };

    float4 a0l = *(const float4*)(ag);
    float4 a0h = *(const float4*)(ag + 4);
    float4 a1l = *(const float4*)(ag + (size_t)64 * D_MODEL);
    float4 a1h = *(const float4*)(ag + (size_t)64 * D_MODEL + 4);
    float4 b0l = *(const float4*)(bg);
    float4 b0h = *(const float4*)(bg + 4);
    float4 b1l = *(const float4*)(bg + (size_t)64 * D_MODEL);
    float4 b1h = *(const float4*)(bg + (size_t)64 * D_MODEL + 4);
    *(uint4v*)&bufA[0][srow * 32 + ssw]        = cvt8(a0l, a0h);
    *(uint4v*)&bufA[0][(64 + srow) * 32 + ssw] = cvt8(a1l, a1h);
    *(uint4v*)&bufB[0][srow * 32 + ssw]        = cvt8(b0l, b0h);
    *(uint4v*)&bufB[0][(64 + srow) * 32 + ssw] = cvt8(b1l, b1h);
    a0l = *(const float4*)(ag + 32);
    a0h = *(const float4*)(ag + 36);
    a1l = *(const float4*)(ag + 32 + (size_t)64 * D_MODEL);
    a1h = *(const float4*)(ag + 36 + (size_t)64 * D_MODEL);
    b0l = *(const float4*)(bg + 32);
    b0h = *(const float4*)(bg + 36);
    b1l = *(const float4*)(bg + 32 + (size_t)64 * D_MODEL);
    b1h = *(const float4*)(bg + 36 + (size_t)64 * D_MODEL);

    for (int k = 0; k < 32; k++) {
        __syncthreads();
        if (k + 1 < 32) {
            short* bA = bufA[(k + 1) & 1];
            short* bB = bufB[(k + 1) & 1];
            *(uint4v*)&bA[srow * 32 + ssw]        = cvt8(a0l, a0h);
            *(uint4v*)&bA[(64 + srow) * 32 + ssw] = cvt8(a1l, a1h);
            *(uint4v*)&bB[srow * 32 + ssw]        = cvt8(b0l, b0h);
            *(uint4v*)&bB[(64 + srow) * 32 + ssw] = cvt8(b1l, b1h);
        }
        if (k + 2 < 32) {
            const int off = (k + 2) * 32;
            a0l = *(const float4*)(ag + off);
            a0h = *(const float4*)(ag + off + 4);
            a1l = *(const float4*)(ag + off + (size_t)64 * D_MODEL);
            a1h = *(const float4*)(ag + off + 4 + (size_t)64 * D_MODEL);
            b0l = *(const float4*)(bg + off);
            b0h = *(const float4*)(bg + off + 4);
            b1l = *(const float4*)(bg + off + (size_t)64 * D_MODEL);
            b1h = *(const float4*)(bg + off + 4 + (size_t)64 * D_MODEL);
        }
        const short* lA = bufA[k & 1];
        const short* lB = bufB[k & 1];
        short8 af[4], bf[4];
        #pragma unroll
        for (int i = 0; i < 4; i++)
            af[i] = *(const short8*)&lA[(mw + i * 16 + l15) * 32 + (quad ^ xsw) * 8];
        #pragma unroll
        for (int i = 0; i < 4; i++)
            bf[i] = *(const short8*)&lB[(nw + i * 16 + l15) * 32 + (quad ^ xsw) * 8];
        #pragma unroll
        for (int mi = 0; mi < 4; mi++)
            #pragma unroll
            for (int ni = 0; ni < 4; ni++)
                acc[mi][ni] = __builtin_amdgcn_mfma_f32_16x16x32_bf16(
                    af[mi], bf[ni], acc[mi][ni], 0, 0, 0);
    }
}

// ---------------------------------------------------------------------------
// out GEMM core: 128x64 tile (R17-proven, 2 blocks/CU). A = Ab (bf16),
// B = wo (FP32, converted in-flight — same cvt_pk path as qkv).
// ---------------------------------------------------------------------------
__device__ __forceinline__ void gemm_core_out(
    const short* __restrict__ a, const float* __restrict__ b,
    short* smem, int m0, int n0, float4v acc[2][4])
{
    const int tid = threadIdx.x;
    const int lane = tid & 63;
    const int l15 = lane & 15, quad = lane >> 4;
    const int wave = tid >> 6;
    const int mw = wave * 32;
    const int srow = tid >> 2;             // 0..63
    const int scol = (tid & 3) * 8;
    const int ssw = (((tid & 3) ^ ((srow >> 1) & 3))) * 8;
    const int xsw = (l15 >> 1) & 3;

    const short* ag = a + (size_t)(m0 + srow) * D_MODEL + scol;
    const float* bg = b + (size_t)(n0 + srow) * D_MODEL + scol;

    short* bufA[2] = { smem,        smem + 6144 };   // 4096 sh each
    short* bufB[2] = { smem + 4096, smem + 10240 };  // 2048 sh each

    short8 ga0 = *(const short8*)(ag);
    short8 ga1 = *(const short8*)(ag + (size_t)64 * D_MODEL);
    float4 b0l = *(const float4*)(bg);
    float4 b0h = *(const float4*)(bg + 4);
    *(short8*)&bufA[0][srow * 32 + ssw]        = ga0;
    *(short8*)&bufA[0][(64 + srow) * 32 + ssw] = ga1;
    *(uint4v*)&bufB[0][srow * 32 + ssw]        = cvt8(b0l, b0h);
    ga0 = *(const short8*)(ag + 32);
    ga1 = *(const short8*)(ag + 32 + (size_t)64 * D_MODEL);
    b0l = *(const float4*)(bg + 32);
    b0h = *(const float4*)(bg + 36);

    for (int k = 0; k < 32; k++) {
        __syncthreads();
        if (k + 1 < 32) {
            short* bA = bufA[(k + 1) & 1];
            short* bB = bufB[(k + 1) & 1];
            *(short8*)&bA[srow * 32 + ssw]        = ga0;
            *(short8*)&bA[(64 + srow) * 32 + ssw] = ga1;
            *(uint4v*)&bB[srow * 32 + ssw]        = cvt8(b0l, b0h);
        }
        if (k + 2 < 32) {
            const int off = (k + 2) * 32;
            ga0 = *(const short8*)(ag + off);
            ga1 = *(const short8*)(ag + off + (size_t)64 * D_MODEL);
            b0l = *(const float4*)(bg + off);
            b0h = *(const float4*)(bg + off + 4);
        }
        const short* lA = bufA[k & 1];
        const short* lB = bufB[k & 1];
        short8 af[2], bf[4];
        #pragma unroll
        for (int i = 0; i < 2; i++)
            af[i] = *(const short8*)&lA[(mw + i * 16 + l15) * 32 + (quad ^ xsw) * 8];
        #pragma unroll
        for (int i = 0; i < 4; i++)
            bf[i] = *(const short8*)&lB[(i * 16 + l15) * 32 + (quad ^ xsw) * 8];
        #pragma unroll
        for (int mi = 0; mi < 2; mi++)
            #pragma unroll
            for (int ni = 0; ni < 4; ni++)
                acc[mi][ni] = __builtin_amdgcn_mfma_f32_16x16x32_bf16(
                    af[mi], bf[ni], acc[mi][ni], 0, 0, 0);
    }
}

// ---------------------------------------------------------------------------
// Kernel 1: fused QKV projection from FP32 sources. R25: cvt kernel deleted;
// conversion happens in the staging pipeline; RoPE trig computed inline via
// raw v_fract/v_sin/v_cos asm (NOT libm). Q pre-scale folds log2(e) so attn
// uses raw v_exp_f32.
// ---------------------------------------------------------------------------
__global__ __launch_bounds__(256) void qkv_mfma_kernel(
    const float* __restrict__ x, const float* __restrict__ wq,
    const float* __restrict__ wk, const float* __restrict__ wv,
    const int* __restrict__ pos,
    short* __restrict__ Qb, short* __restrict__ Kb, short* __restrict__ Vt)
{
    __shared__ __align__(16) short smem[128 * 136];

    const int z = blockIdx.x >> 8;
    const int bid = blockIdx.x & 255;
    const int m0 = (bid & 31) * 128;
    const int n0 = (bid >> 5) * 128;
    const float* w = (z == 0) ? wq : (z == 1) ? wk : wv;

    float4v acc[4][4];
    #pragma unroll
    for (int i = 0; i < 4; i++)
        #pragma unroll
        for (int j = 0; j < 4; j++)
            acc[i][j] = (float4v){0.f, 0.f, 0.f, 0.f};

    gemm_core_f32(x, w, smem, m0, n0, acc);

    const int tid = threadIdx.x;
    const int lane = tid & 63;
    const int l15 = lane & 15, quad = lane >> 4;
    const int wave = tid >> 6;
    const int mw = (wave & 1) * 64, nw = (wave >> 1) * 64;
    const int s_base = m0 & (SEQ - 1);
    const int bb = m0 >> 11;

    __syncthreads();

    if (z == 2) {
        #pragma unroll
        for (int ni = 0; ni < 4; ni++) {
            #pragma unroll
            for (int mi = 0; mi < 4; mi++) {
                #pragma unroll
                for (int r = 0; r < 4; r++)
                    smem[(nw + ni * 16 + l15) * 136 + mw + mi * 16 + quad * 4 + r] =
                        f2bf(acc[mi][ni][r]);
            }
        }
        __syncthreads();
        #pragma unroll
        for (int it = 0; it < 8; it++) {
            const int nloc = it * 16 + (tid >> 4);
            const int mloc = (tid & 15) * 8;
            const short8 val = *(const short8*)&smem[nloc * 136 + mloc];
            const int n = n0 + nloc;
            const int h = n >> 6, d = n & 63;
            *(short8*)(Vt + ((size_t)(bb * NUM_HEADS + h) * D_HEAD + d) * SEQ +
                       s_base + mloc) = val;
        }
    } else {
        short* dst = (z == 0) ? Qb : Kb;
        // 0.125 = 1/sqrt(64); * log2(e): scores land in exp2 domain.
        const float qs = (z == 0) ? 0.18033688011112042f : 1.0f;

        // token positions for this lane's 16 rows (rule #20: unrolled idx)
        float pf[4][4];
        #pragma unroll
        for (int mi = 0; mi < 4; mi++)
            #pragma unroll
            for (int r = 0; r < 4; r++)
                pf[mi][r] = (float)pos[s_base + mw + mi * 16 + quad * 4 + r];

        #pragma unroll
        for (int ni = 0; ni < 4; ni++) {
            const int n = n0 + nw + ni * 16 + l15;
            const int d = n & 63;
            const int fi = d >> 1;
            // inv_freq / (2*pi): v_sin/v_cos take revolutions
            const float invrev = fexp2((float)fi * -0.4152410118609203f) *
                                 0.15915494309189535f;
            #pragma unroll
            for (int mi = 0; mi < 4; mi++) {
                #pragma unroll
                for (int r = 0; r < 4; r++) {
                    const int mloc = mw + mi * 16 + quad * 4 + r;
                    float sn, cs;
                    sincos_rev(pf[mi][r] * invrev, &sn, &cs);
                    const float val = acc[mi][ni][r];
                    const float partner = __shfl_xor(val, 1, 64);
                    const float res = (l15 & 1) ? fmaf(partner, sn, val * cs)
                                                : fmaf(val, cs, -partner * sn);
                    smem[mloc * 136 + nw + ni * 16 + l15] = f2bf(res * qs);
                }
            }
        }
        __syncthreads();
        #pragma unroll
        for (int it = 0; it < 8; it++) {
            const int ri = it * 32 + (tid >> 3);
            const int mloc = ri & 127;
            const int hh = ri >> 7;
            const int nloc = hh * 64 + (tid & 7) * 8;
            const short8 val = *(const short8*)&smem[mloc * 136 + nloc];
            const int n = n0 + nloc;
            const int h = n >> 6, d = n & 63;
            *(short8*)(dst + ((size_t)(bb * NUM_HEADS + h) * SEQ + s_base + mloc) *
                       D_HEAD + d) = val;
        }
    }
}

// ---------------------------------------------------------------------------
// Kernel 2: causal flash attention (R15/R16 structure: measured-clean LDS
// layouts, setprio, exp2-domain scores — byte-identical control group).
// ---------------------------------------------------------------------------
__global__ __launch_bounds__(256) void attn_mfma_kernel(
    const short* __restrict__ Qb, const short* __restrict__ Kb,
    const short* __restrict__ Vt, short* __restrict__ Ab)
{
    __shared__ __align__(16) short lKa[64 * 32];
    __shared__ __align__(16) short lKb[64 * 32];
    __shared__ __align__(16) short lVa[64 * 32];
    __shared__ __align__(16) short lVb[64 * 32];
    __shared__ __align__(16) short lP[4][2][16 * 32];

    const int tid = threadIdx.x;
    const int lane = tid & 63;
    const int wave = tid >> 6;
    const int l15 = lane & 15;
    const int quad = lane >> 4;

    const int bh = blockIdx.x & (BATCH * NUM_HEADS - 1);
    const int qt = (SEQ / 64 - 1) - (blockIdx.x >> 5);   // longest first
    const int q0w = qt * 64 + wave * 16;
    const int qcmp = q0w + l15;

    const short* Kg = Kb + (size_t)bh * SEQ * D_HEAD;
    const short* Vg = Vt + (size_t)bh * D_HEAD * SEQ;

    const short* Qrow = Qb + ((size_t)bh * SEQ + q0w + l15) * D_HEAD;
    const short8 qf0 = *(const short8*)(Qrow + quad * 8);
    const short8 qf1 = *(const short8*)(Qrow + 32 + quad * 8);

    float4v o0 = {0.f, 0.f, 0.f, 0.f}, o1 = o0, o2 = o0, o3 = o0;
    float lpA = 0.f, lpB = 0.f;

    const int nt = qt + 1;                 // 64-key tiles
    const int srow = tid >> 2;             // 0..63
    const int c4  = tid & 3;               // chunk 0..3
    const int sch = c4 * 8;                // global source offset (shorts)
    const int swoff = srow * 32 + ((c4 ^ ((srow >> 1) & 3)) * 8);  // staging dest
    const int xsw = (l15 >> 1) & 3;        // read-side swizzle term

    short8 k0 = *(const short8*)(Kg + (size_t)srow * D_HEAD + sch);
    short8 k1 = *(const short8*)(Kg + (size_t)srow * D_HEAD + sch + 32);
    short8 v0 = *(const short8*)(Vg + (size_t)srow * SEQ + sch);
    short8 v1 = *(const short8*)(Vg + (size_t)srow * SEQ + sch + 32);

#define ATTN_TILE_COMPUTE(KT0, MASKED)                                        \
    {                                                                         \
        short* PwA = &lP[wave][0][0];                                         \
        short* PwB = &lP[wave][1][0];                                         \
        _Pragma("unroll")                                                     \
        for (int g = 0; g < 4; g++) {                                         \
            float4v s = {0.f, 0.f, 0.f, 0.f};                                 \
            const int krow = (g * 16 + l15) * 32 + (quad ^ xsw) * 8;          \
            const short8 ka = *(const short8*)&lKa[krow];                     \
            const short8 kb = *(const short8*)&lKb[krow];                     \
            __builtin_amdgcn_s_setprio(1);                                    \
            s = __builtin_amdgcn_mfma_f32_16x16x32_bf16(ka, qf0, s, 0, 0, 0); \
            s = __builtin_amdgcn_mfma_f32_16x16x32_bf16(kb, qf1, s, 0, 0, 0); \
            __builtin_amdgcn_s_setprio(0);                                    \
            float e0, e1, e2, e3;                                             \
            if (MASKED) {                                                     \
                const int kbase = (KT0) + g * 16 + quad * 4;                  \
                e0 = (kbase + 0 <= qcmp) ? fexp2(s[0]) : 0.f;                 \
                e1 = (kbase + 1 <= qcmp) ? fexp2(s[1]) : 0.f;                 \
                e2 = (kbase + 2 <= qcmp) ? fexp2(s[2]) : 0.f;                 \
                e3 = (kbase + 3 <= qcmp) ? fexp2(s[3]) : 0.f;                 \
            } else {                                                          \
                e0 = fexp2(s[0]); e1 = fexp2(s[1]);                           \
                e2 = fexp2(s[2]); e3 = fexp2(s[3]);                           \
            }                                                                 \
            lpA += e0 + e2;                                                   \
            lpB += e1 + e3;                                                   \
            unsigned int pw0, pw1;                                            \
            asm("v_cvt_pk_bf16_f32 %0, %1, %2" : "=v"(pw0) : "v"(e0), "v"(e1)); \
            asm("v_cvt_pk_bf16_f32 %0, %1, %2" : "=v"(pw1) : "v"(e2), "v"(e3)); \
            uint2v pk; pk[0] = pw0; pk[1] = pw1;                              \
            short* Pd = (g < 2) ? PwA : PwB;                                  \
            const int ps = ((((g & 1) * 2 + (quad >> 1)) ^ xsw) * 8) +        \
                           (quad & 1) * 4;                                    \
            *(uint2v*)&Pd[l15 * 32 + ps] = pk;                                \
        }                                                                     \
        const int prow = l15 * 32 + (quad ^ xsw) * 8;                         \
        const short8 pa0 = *(const short8*)&PwA[prow];                        \
        const short8 pa1 = *(const short8*)&PwB[prow];                        \
        __builtin_amdgcn_s_setprio(1);                                        \
        _Pragma("unroll")                                                     \
        for (int j = 0; j < 4; j++) {                                         \
            const int vrow = (j * 16 + l15) * 32 + (quad ^ xsw) * 8;          \
            const short8 va = *(const short8*)&lVa[vrow];                     \
            const short8 vb = *(const short8*)&lVb[vrow];                     \
            float4v* oj = (j == 0) ? &o0 : (j == 1) ? &o1 : (j == 2) ? &o2 : &o3;       \
            *oj = __builtin_amdgcn_mfma_f32_16x16x32_bf16(pa0, va, *oj, 0, 0, 0);       \
            *oj = __builtin_amdgcn_mfma_f32_16x16x32_bf16(pa1, vb, *oj, 0, 0, 0);       \
        }                                                                     \
        __builtin_amdgcn_s_setprio(0);                                        \
    }

    for (int t = 0; t < nt - 1; t++) {
        const int kt0 = t * 64;
        __syncthreads();
        *(short8*)&lKa[swoff] = k0;
        *(short8*)&lKb[swoff] = k1;
        *(short8*)&lVa[swoff] = v0;
        *(short8*)&lVb[swoff] = v1;
        __syncthreads();
        k0 = *(const short8*)(Kg + (size_t)(kt0 + 64 + srow) * D_HEAD + sch);
        k1 = *(const short8*)(Kg + (size_t)(kt0 + 64 + srow) * D_HEAD + sch + 32);
        v0 = *(const short8*)(Vg + (size_t)srow * SEQ + kt0 + 64 + sch);
        v1 = *(const short8*)(Vg + (size_t)srow * SEQ + kt0 + 64 + sch + 32);
        ATTN_TILE_COMPUTE(kt0, false)
    }
    {
        const int kt0 = (nt - 1) * 64;
        __syncthreads();
        *(short8*)&lKa[swoff] = k0;
        *(short8*)&lKb[swoff] = k1;
        *(short8*)&lVa[swoff] = v0;
        *(short8*)&lVb[swoff] = v1;
        __syncthreads();
        ATTN_TILE_COMPUTE(kt0, true)
    }
#undef ATTN_TILE_COMPUTE

    // lp totals: q = l15 replicated across quad groups
    float lp = lpA + lpB;
    lp += __shfl_xor(lp, 16, 64);
    lp += __shfl_xor(lp, 32, 64);

    const int b = bh >> 4, h = bh & 15;
    short* Ap = Ab + ((size_t)(b * SEQ) + q0w + quad * 4) * D_MODEL + h * D_HEAD;
    #pragma unroll
    for (int r = 0; r < 4; r++) {
        const float inv = 1.0f / __shfl(lp, quad * 4 + r, 64);
        Ap[(size_t)r * D_MODEL + l15]      = f2bf(o0[r] * inv);
        Ap[(size_t)r * D_MODEL + 16 + l15] = f2bf(o1[r] * inv);
        Ap[(size_t)r * D_MODEL + 32 + l15] = f2bf(o2[r] * inv);
        Ap[(size_t)r * D_MODEL + 48 + l15] = f2bf(o3[r] * inv);
    }
}

// ---------------------------------------------------------------------------
// Kernel 3: output projection (R17 geometry; B = wo fp32 inline-converted).
// ---------------------------------------------------------------------------
__global__ __launch_bounds__(256) void out_mfma_kernel(
    const short* __restrict__ Ab, const float* __restrict__ wo,
    float* __restrict__ out)
{
    __shared__ __align__(16) short smem[12288];

    const int bid = blockIdx.x;
    const int m0 = (bid & 31) * 128;
    const int n0 = (bid >> 5) * 64;

    float4v acc[2][4];
    #pragma unroll
    for (int i = 0; i < 2; i++)
        #pragma unroll
        for (int j = 0; j < 4; j++)
            acc[i][j] = (float4v){0.f, 0.f, 0.f, 0.f};

    gemm_core_out(Ab, wo, smem, m0, n0, acc);

    const int tid = threadIdx.x;
    const int lane = tid & 63;
    const int l15 = lane & 15, quad = lane >> 4;
    const int wave = tid >> 6;
    const int mw = wave * 32;

    #pragma unroll
    for (int mi = 0; mi < 2; mi++) {
        #pragma unroll
        for (int r = 0; r < 4; r++) {
            const int m = m0 + mw + mi * 16 + quad * 4 + r;
            float* op = out + (size_t)m * D_MODEL + n0 + l15;
            #pragma unroll
            for (int ni = 0; ni < 4; ni++)
                op[ni * 16] = acc[mi][ni][r];
        }
    }
}

// ---------------------------------------------------------------------------
extern "C" void kernel_launch(void* const* d_in, const int* in_sizes, int n_in,
                              void* d_out, int out_size, void* d_ws, size_t ws_size,
                              hipStream_t stream)
{
    const float* x  = (const float*)d_in[0];
    const int*  pos = (const int*)d_in[1];
    const float* wq = (const float*)d_in[2];
    const float* wk = (const float*)d_in[3];
    const float* wv = (const float*)d_in[4];
    const float* wo = (const float*)d_in[5];
    float* out = (float*)d_out;

    const size_t nx = (size_t)BATCH * SEQ * D_MODEL;   // 4M
    short* Qb  = (short*)d_ws;
    short* Kb  = Qb + nx;
    short* Vt  = Kb + nx;
    short* Ab  = Vt + nx;

    dim3 blk(256);
    qkv_mfma_kernel<<<dim3(768), blk, 0, stream>>>(x, wq, wk, wv, pos,
                                                   Qb, Kb, Vt);
    attn_mfma_kernel<<<dim3(BATCH * NUM_HEADS * (SEQ / 64)), blk, 0, stream>>>(Qb, Kb, Vt, Ab);
    out_mfma_kernel<<<dim3(512), blk, 0, stream>>>(Ab, wo, out);
}

// Round 18
// 173.619 us; speedup vs baseline: 1.1994x; 1.1994x over previous
//
#include <hip/hip_runtime.h>
#include <math.h>

#define D_MODEL 1024
#define NUM_HEADS 16
#define D_HEAD 64
#define SEQ 2048
#define BATCH 2

typedef __attribute__((ext_vector_type(8))) short short8;
typedef __attribute__((ext_vector_type(4))) short short4v;
typedef __attribute__((ext_vector_type(4))) float float4v;
typedef __attribute__((ext_vector_type(2))) unsigned int uint2v;

__device__ __forceinline__ short f2bf(float f) {
    unsigned u = __float_as_uint(f);
    u += 0x7FFFu + ((u >> 16) & 1u);
    return (short)(u >> 16);
}

__device__ __forceinline__ float fexp2(float x) {
    return __builtin_amdgcn_exp2f(x);      // raw v_exp_f32 (exp2 domain)
}

// ---------------------------------------------------------------------------
// Kernel 0: fp32 -> bf16 conversion + RoPE cos/sin table (all libm here;
// NEVER in hot MFMA kernels — sincosf codegen poisons them). R17 lesson:
// this kernel is load-bearing — pre-converting once halves all downstream
// global traffic and keeps GEMM staging pure data-movement.
// ---------------------------------------------------------------------------
__global__ __launch_bounds__(256) void cvt_bf16_kernel(
    const float* __restrict__ x,  const float* __restrict__ wq,
    const float* __restrict__ wk, const float* __restrict__ wv,
    const float* __restrict__ wo, const int* __restrict__ pos,
    short* __restrict__ xb,  short* __restrict__ wqb,
    short* __restrict__ wkb, short* __restrict__ wvb,
    short* __restrict__ wob,
    float* __restrict__ costab, float* __restrict__ sintab)
{
    const int a = blockIdx.y;
    if (a == 5) {                          // RoPE table: idx = s*32 + fi
        const int idx = blockIdx.x * 256 + threadIdx.x;
        if (idx < SEQ * 32) {
            const int s = idx >> 5, fi = idx & 31;
            const float p = (float)pos[s];
            const float inv_freq = exp2f((float)fi * -0.4152410118609203f);
            float sn, cs;
            sincosf(p * inv_freq, &sn, &cs);
            costab[idx] = cs;
            sintab[idx] = sn;
        }
        return;
    }
    const float* src = (a == 0) ? x : (a == 1) ? wq : (a == 2) ? wk : (a == 3) ? wv : wo;
    short* dst = (a == 0) ? xb : (a == 1) ? wqb : (a == 2) ? wkb : (a == 3) ? wvb : wob;
    const int n = (a == 0) ? (BATCH * SEQ * D_MODEL) : (D_MODEL * D_MODEL);
    const int i = (blockIdx.x * 256 + threadIdx.x) * 8;
    if (i >= n) return;
    const float4 v0 = *(const float4*)(src + i);
    const float4 v1 = *(const float4*)(src + i + 4);
    short8 r;
    r[0] = f2bf(v0.x); r[1] = f2bf(v0.y); r[2] = f2bf(v0.z); r[3] = f2bf(v0.w);
    r[4] = f2bf(v1.x); r[5] = f2bf(v1.y); r[6] = f2bf(v1.z); r[7] = f2bf(v1.w);
    *(short8*)(dst + i) = r;
}

// ---------------------------------------------------------------------------
// bf16 MFMA GEMM core, reg-staged (proven: 2-deep register pipeline + XOR
// bank swizzle; conflicts measured 229K). Survived 6 attacks — keep as-is.
// ---------------------------------------------------------------------------
__device__ __forceinline__ void gemm_core_db(
    const short* __restrict__ a, const short* __restrict__ b,
    short* smem, int m0, int n0, float4v acc[4][4], const int nk)
{
    const int tid = threadIdx.x;
    const int lane = tid & 63;
    const int l15 = lane & 15, quad = lane >> 4;
    const int wave = tid >> 6;
    const int mw = (wave & 1) * 64, nw = (wave >> 1) * 64;
    const int srow = tid >> 2;
    const int scol = (tid & 3) * 8;
    const int ssw = (((tid & 3) ^ ((srow >> 1) & 3))) * 8;
    const int xsw = (l15 >> 1) & 3;

    const short* ag = a + (size_t)(m0 + srow) * D_MODEL + scol;
    const short* bg = b + (size_t)(n0 + srow) * D_MODEL + scol;

    short* bufA[2] = { smem,        smem + 8192 };
    short* bufB[2] = { smem + 4096, smem + 12288 };

    short8 ga0 = *(const short8*)(ag);
    short8 ga1 = *(const short8*)(ag + (size_t)64 * D_MODEL);
    short8 gb0 = *(const short8*)(bg);
    short8 gb1 = *(const short8*)(bg + (size_t)64 * D_MODEL);
    *(short8*)&bufA[0][srow * 32 + ssw]        = ga0;
    *(short8*)&bufA[0][(64 + srow) * 32 + ssw] = ga1;
    *(short8*)&bufB[0][srow * 32 + ssw]        = gb0;
    *(short8*)&bufB[0][(64 + srow) * 32 + ssw] = gb1;
    ga0 = *(const short8*)(ag + 32);
    ga1 = *(const short8*)(ag + 32 + (size_t)64 * D_MODEL);
    gb0 = *(const short8*)(bg + 32);
    gb1 = *(const short8*)(bg + 32 + (size_t)64 * D_MODEL);

    for (int k = 0; k < nk; k++) {
        __syncthreads();
        if (k + 1 < nk) {
            short* bA = bufA[(k + 1) & 1];
            short* bB = bufB[(k + 1) & 1];
            *(short8*)&bA[srow * 32 + ssw]        = ga0;
            *(short8*)&bA[(64 + srow) * 32 + ssw] = ga1;
            *(short8*)&bB[srow * 32 + ssw]        = gb0;
            *(short8*)&bB[(64 + srow) * 32 + ssw] = gb1;
        }
        if (k + 2 < nk) {
            const int off = (k + 2) * 32;
            ga0 = *(const short8*)(ag + off);
            ga1 = *(const short8*)(ag + off + (size_t)64 * D_MODEL);
            gb0 = *(const short8*)(bg + off);
            gb1 = *(const short8*)(bg + off + (size_t)64 * D_MODEL);
        }
        const short* lA = bufA[k & 1];
        const short* lB = bufB[k & 1];
        short8 af[4], bf[4];
        #pragma unroll
        for (int i = 0; i < 4; i++)
            af[i] = *(const short8*)&lA[(mw + i * 16 + l15) * 32 + (quad ^ xsw) * 8];
        #pragma unroll
        for (int i = 0; i < 4; i++)
            bf[i] = *(const short8*)&lB[(nw + i * 16 + l15) * 32 + (quad ^ xsw) * 8];
        #pragma unroll
        for (int mi = 0; mi < 4; mi++)
            #pragma unroll
            for (int ni = 0; ni < 4; ni++)
                acc[mi][ni] = __builtin_amdgcn_mfma_f32_16x16x32_bf16(
                    af[mi], bf[ni], acc[mi][ni], 0, 0, 0);
    }
}

// ---------------------------------------------------------------------------
// bf16 MFMA GEMM core for out: 128x64 tile (R17-geometry-proven, 2 blocks/CU).
// ---------------------------------------------------------------------------
__device__ __forceinline__ void gemm_core_out(
    const short* __restrict__ a, const short* __restrict__ b,
    short* smem, int m0, int n0, float4v acc[2][4])
{
    const int tid = threadIdx.x;
    const int lane = tid & 63;
    const int l15 = lane & 15, quad = lane >> 4;
    const int wave = tid >> 6;
    const int mw = wave * 32;
    const int srow = tid >> 2;             // 0..63
    const int scol = (tid & 3) * 8;
    const int ssw = (((tid & 3) ^ ((srow >> 1) & 3))) * 8;
    const int xsw = (l15 >> 1) & 3;

    const short* ag = a + (size_t)(m0 + srow) * D_MODEL + scol;
    const short* bg = b + (size_t)(n0 + srow) * D_MODEL + scol;

    short* bufA[2] = { smem,        smem + 6144 };   // 4096 sh each
    short* bufB[2] = { smem + 4096, smem + 10240 };  // 2048 sh each

    short8 ga0 = *(const short8*)(ag);
    short8 ga1 = *(const short8*)(ag + (size_t)64 * D_MODEL);
    short8 gb0 = *(const short8*)(bg);
    *(short8*)&bufA[0][srow * 32 + ssw]        = ga0;
    *(short8*)&bufA[0][(64 + srow) * 32 + ssw] = ga1;
    *(short8*)&bufB[0][srow * 32 + ssw]        = gb0;
    ga0 = *(const short8*)(ag + 32);
    ga1 = *(const short8*)(ag + 32 + (size_t)64 * D_MODEL);
    gb0 = *(const short8*)(bg + 32);

    for (int k = 0; k < 32; k++) {
        __syncthreads();
        if (k + 1 < 32) {
            short* bA = bufA[(k + 1) & 1];
            short* bB = bufB[(k + 1) & 1];
            *(short8*)&bA[srow * 32 + ssw]        = ga0;
            *(short8*)&bA[(64 + srow) * 32 + ssw] = ga1;
            *(short8*)&bB[srow * 32 + ssw]        = gb0;
        }
        if (k + 2 < 32) {
            const int off = (k + 2) * 32;
            ga0 = *(const short8*)(ag + off);
            ga1 = *(const short8*)(ag + off + (size_t)64 * D_MODEL);
            gb0 = *(const short8*)(bg + off);
        }
        const short* lA = bufA[k & 1];
        const short* lB = bufB[k & 1];
        short8 af[2], bf[4];
        #pragma unroll
        for (int i = 0; i < 2; i++)
            af[i] = *(const short8*)&lA[(mw + i * 16 + l15) * 32 + (quad ^ xsw) * 8];
        #pragma unroll
        for (int i = 0; i < 4; i++)
            bf[i] = *(const short8*)&lB[(i * 16 + l15) * 32 + (quad ^ xsw) * 8];
        #pragma unroll
        for (int mi = 0; mi < 2; mi++)
            #pragma unroll
            for (int ni = 0; ni < 4; ni++)
                acc[mi][ni] = __builtin_amdgcn_mfma_f32_16x16x32_bf16(
                    af[mi], bf[ni], acc[mi][ni], 0, 0, 0);
    }
}

// ---------------------------------------------------------------------------
// Kernel 1: fused QKV projection (R9-proven). Q pre-scale folds log2(e).
// ---------------------------------------------------------------------------
__global__ __launch_bounds__(256) void qkv_mfma_kernel(
    const short* __restrict__ xb, const short* __restrict__ wqb,
    const short* __restrict__ wkb, const short* __restrict__ wvb,
    const float* __restrict__ costab, const float* __restrict__ sintab,
    short* __restrict__ Qb, short* __restrict__ Kb, short* __restrict__ Vt)
{
    __shared__ __align__(16) short smem[128 * 136];

    const int z = blockIdx.x >> 8;
    const int bid = blockIdx.x & 255;
    const int m0 = (bid & 31) * 128;
    const int n0 = (bid >> 5) * 128;
    const short* w = (z == 0) ? wqb : (z == 1) ? wkb : wvb;

    float4v acc[4][4];
    #pragma unroll
    for (int i = 0; i < 4; i++)
        #pragma unroll
        for (int j = 0; j < 4; j++)
            acc[i][j] = (float4v){0.f, 0.f, 0.f, 0.f};

    gemm_core_db(xb, w, smem, m0, n0, acc, 32);

    const int tid = threadIdx.x;
    const int lane = tid & 63;
    const int l15 = lane & 15, quad = lane >> 4;
    const int wave = tid >> 6;
    const int mw = (wave & 1) * 64, nw = (wave >> 1) * 64;
    const int s_base = m0 & (SEQ - 1);
    const int bb = m0 >> 11;

    __syncthreads();

    if (z == 2) {
        #pragma unroll
        for (int ni = 0; ni < 4; ni++) {
            #pragma unroll
            for (int mi = 0; mi < 4; mi++) {
                #pragma unroll
                for (int r = 0; r < 4; r++)
                    smem[(nw + ni * 16 + l15) * 136 + mw + mi * 16 + quad * 4 + r] =
                        f2bf(acc[mi][ni][r]);
            }
        }
        __syncthreads();
        #pragma unroll
        for (int it = 0; it < 8; it++) {
            const int nloc = it * 16 + (tid >> 4);
            const int mloc = (tid & 15) * 8;
            const short8 val = *(const short8*)&smem[nloc * 136 + mloc];
            const int n = n0 + nloc;
            const int h = n >> 6, d = n & 63;
            *(short8*)(Vt + ((size_t)(bb * NUM_HEADS + h) * D_HEAD + d) * SEQ +
                       s_base + mloc) = val;
        }
    } else {
        short* dst = (z == 0) ? Qb : Kb;
        // 0.125 = 1/sqrt(64); * log2(e) so scores are already in exp2 domain.
        const float qs = (z == 0) ? 0.18033688011112042f : 1.0f;
        #pragma unroll
        for (int ni = 0; ni < 4; ni++) {
            const int n = n0 + nw + ni * 16 + l15;
            const int d = n & 63;
            const int fi = d >> 1;
            #pragma unroll
            for (int mi = 0; mi < 4; mi++) {
                #pragma unroll
                for (int r = 0; r < 4; r++) {
                    const int mloc = mw + mi * 16 + quad * 4 + r;
                    const int ti = ((s_base + mloc) << 5) + fi;
                    const float cs = costab[ti];
                    const float sn = sintab[ti];
                    const float val = acc[mi][ni][r];
                    const float partner = __shfl_xor(val, 1, 64);
                    const float res = (l15 & 1) ? fmaf(partner, sn, val * cs)
                                                : fmaf(val, cs, -partner * sn);
                    smem[mloc * 136 + nw + ni * 16 + l15] = f2bf(res * qs);
                }
            }
        }
        __syncthreads();
        #pragma unroll
        for (int it = 0; it < 8; it++) {
            const int ri = it * 32 + (tid >> 3);
            const int mloc = ri & 127;
            const int hh = ri >> 7;
            const int nloc = hh * 64 + (tid & 7) * 8;
            const short8 val = *(const short8*)&smem[mloc * 136 + nloc];
            const int n = n0 + nloc;
            const int h = n >> 6, d = n & 63;
            *(short8*)(dst + ((size_t)(bb * NUM_HEADS + h) * SEQ + s_base + mloc) *
                       D_HEAD + d) = val;
        }
    }
}

// ---------------------------------------------------------------------------
// Kernel 2: causal flash attention (R15 best: measured-clean K/V layout,
// 72-stride lP, VALU package, setprio).
// ---------------------------------------------------------------------------
__global__ __launch_bounds__(256) void attn_mfma_kernel(
    const short* __restrict__ Qb, const short* __restrict__ Kb,
    const short* __restrict__ Vt, short* __restrict__ Ab)
{
    __shared__ __align__(16) short lKa[64 * 32];
    __shared__ __align__(16) short lKb[64 * 32];
    __shared__ __align__(16) short lVa[64 * 32];
    __shared__ __align__(16) short lVb[64 * 32];
    __shared__ __align__(16) short lP[4][16 * 72];

    const int tid = threadIdx.x;
    const int lane = tid & 63;
    const int wave = tid >> 6;
    const int l15 = lane & 15;
    const int quad = lane >> 4;

    const int bh = blockIdx.x & (BATCH * NUM_HEADS - 1);
    const int qt = (SEQ / 64 - 1) - (blockIdx.x >> 5);   // longest first
    const int q0w = qt * 64 + wave * 16;
    const int qcmp = q0w + l15;

    const short* Kg = Kb + (size_t)bh * SEQ * D_HEAD;
    const short* Vg = Vt + (size_t)bh * D_HEAD * SEQ;

    const short* Qrow = Qb + ((size_t)bh * SEQ + q0w + l15) * D_HEAD;
    const short8 qf0 = *(const short8*)(Qrow + quad * 8);
    const short8 qf1 = *(const short8*)(Qrow + 32 + quad * 8);

    float4v o0 = {0.f, 0.f, 0.f, 0.f}, o1 = o0, o2 = o0, o3 = o0;
    float lpA = 0.f, lpB = 0.f;

    const int nt = qt + 1;                 // 64-key tiles
    const int srow = tid >> 2;             // 0..63
    const int c4  = tid & 3;               // chunk 0..3
    const int sch = c4 * 8;                // global source offset (shorts)
    const int swoff = srow * 32 + ((c4 ^ ((srow >> 1) & 3)) * 8);  // staging dest
    const int xsw = (l15 >> 1) & 3;        // read-side swizzle term

    short8 k0 = *(const short8*)(Kg + (size_t)srow * D_HEAD + sch);
    short8 k1 = *(const short8*)(Kg + (size_t)srow * D_HEAD + sch + 32);
    short8 v0 = *(const short8*)(Vg + (size_t)srow * SEQ + sch);
    short8 v1 = *(const short8*)(Vg + (size_t)srow * SEQ + sch + 32);

#define ATTN_TILE_COMPUTE(KT0, MASKED)                                        \
    {                                                                         \
        short* Pw = lP[wave];                                                 \
        _Pragma("unroll")                                                     \
        for (int g = 0; g < 4; g++) {                                         \
            float4v s = {0.f, 0.f, 0.f, 0.f};                                 \
            const int krow = (g * 16 + l15) * 32 + (quad ^ xsw) * 8;          \
            const short8 ka = *(const short8*)&lKa[krow];                     \
            const short8 kb = *(const short8*)&lKb[krow];                     \
            __builtin_amdgcn_s_setprio(1);                                    \
            s = __builtin_amdgcn_mfma_f32_16x16x32_bf16(ka, qf0, s, 0, 0, 0); \
            s = __builtin_amdgcn_mfma_f32_16x16x32_bf16(kb, qf1, s, 0, 0, 0); \
            __builtin_amdgcn_s_setprio(0);                                    \
            float e0, e1, e2, e3;                                             \
            if (MASKED) {                                                     \
                const int kbase = (KT0) + g * 16 + quad * 4;                  \
                e0 = (kbase + 0 <= qcmp) ? fexp2(s[0]) : 0.f;                 \
                e1 = (kbase + 1 <= qcmp) ? fexp2(s[1]) : 0.f;                 \
                e2 = (kbase + 2 <= qcmp) ? fexp2(s[2]) : 0.f;                 \
                e3 = (kbase + 3 <= qcmp) ? fexp2(s[3]) : 0.f;                 \
            } else {                                                          \
                e0 = fexp2(s[0]); e1 = fexp2(s[1]);                           \
                e2 = fexp2(s[2]); e3 = fexp2(s[3]);                           \
            }                                                                 \
            lpA += e0 + e2;                                                   \
            lpB += e1 + e3;                                                   \
            unsigned int pw0, pw1;                                            \
            asm("v_cvt_pk_bf16_f32 %0, %1, %2" : "=v"(pw0) : "v"(e0), "v"(e1)); \
            asm("v_cvt_pk_bf16_f32 %0, %1, %2" : "=v"(pw1) : "v"(e2), "v"(e3)); \
            uint2v pk; pk[0] = pw0; pk[1] = pw1;                              \
            *(uint2v*)&Pw[l15 * 72 + g * 16 + quad * 4] = pk;                 \
        }                                                                     \
        const short8 pa0 = *(const short8*)&lP[wave][l15 * 72 + quad * 8];    \
        const short8 pa1 = *(const short8*)&lP[wave][l15 * 72 + 32 + quad * 8]; \
        __builtin_amdgcn_s_setprio(1);                                        \
        _Pragma("unroll")                                                     \
        for (int j = 0; j < 4; j++) {                                         \
            const int vrow = (j * 16 + l15) * 32 + (quad ^ xsw) * 8;          \
            const short8 va = *(const short8*)&lVa[vrow];                     \
            const short8 vb = *(const short8*)&lVb[vrow];                     \
            float4v* oj = (j == 0) ? &o0 : (j == 1) ? &o1 : (j == 2) ? &o2 : &o3;       \
            *oj = __builtin_amdgcn_mfma_f32_16x16x32_bf16(pa0, va, *oj, 0, 0, 0);       \
            *oj = __builtin_amdgcn_mfma_f32_16x16x32_bf16(pa1, vb, *oj, 0, 0, 0);       \
        }                                                                     \
        __builtin_amdgcn_s_setprio(0);                                        \
    }

    for (int t = 0; t < nt - 1; t++) {
        const int kt0 = t * 64;
        __syncthreads();
        *(short8*)&lKa[swoff] = k0;
        *(short8*)&lKb[swoff] = k1;
        *(short8*)&lVa[swoff] = v0;
        *(short8*)&lVb[swoff] = v1;
        __syncthreads();
        k0 = *(const short8*)(Kg + (size_t)(kt0 + 64 + srow) * D_HEAD + sch);
        k1 = *(const short8*)(Kg + (size_t)(kt0 + 64 + srow) * D_HEAD + sch + 32);
        v0 = *(const short8*)(Vg + (size_t)srow * SEQ + kt0 + 64 + sch);
        v1 = *(const short8*)(Vg + (size_t)srow * SEQ + kt0 + 64 + sch + 32);
        ATTN_TILE_COMPUTE(kt0, false)
    }
    {
        const int kt0 = (nt - 1) * 64;
        __syncthreads();
        *(short8*)&lKa[swoff] = k0;
        *(short8*)&lKb[swoff] = k1;
        *(short8*)&lVa[swoff] = v0;
        *(short8*)&lVb[swoff] = v1;
        __syncthreads();
        ATTN_TILE_COMPUTE(kt0, true)
    }
#undef ATTN_TILE_COMPUTE

    // lp totals: q = l15 replicated across quad groups
    float lp = lpA + lpB;
    lp += __shfl_xor(lp, 16, 64);
    lp += __shfl_xor(lp, 32, 64);

    const int b = bh >> 4, h = bh & 15;
    short* Ap = Ab + ((size_t)(b * SEQ) + q0w + quad * 4) * D_MODEL + h * D_HEAD;
    #pragma unroll
    for (int r = 0; r < 4; r++) {
        const float inv = 1.0f / __shfl(lp, quad * 4 + r, 64);
        Ap[(size_t)r * D_MODEL + l15]      = f2bf(o0[r] * inv);
        Ap[(size_t)r * D_MODEL + 16 + l15] = f2bf(o1[r] * inv);
        Ap[(size_t)r * D_MODEL + 32 + l15] = f2bf(o2[r] * inv);
        Ap[(size_t)r * D_MODEL + 48 + l15] = f2bf(o3[r] * inv);
    }
}

// ---------------------------------------------------------------------------
// Kernel 3: output projection (R9-proven: 128x64 tile, grid 512 =
// 2 blocks/CU, plain stores).
// ---------------------------------------------------------------------------
__global__ __launch_bounds__(256) void out_mfma_kernel(
    const short* __restrict__ Ab, const short* __restrict__ wob,
    float* __restrict__ out)
{
    __shared__ __align__(16) short smem[12288];

    const int bid = blockIdx.x;
    const int m0 = (bid & 31) * 128;
    const int n0 = (bid >> 5) * 64;

    float4v acc[2][4];
    #pragma unroll
    for (int i = 0; i < 2; i++)
        #pragma unroll
        for (int j = 0; j < 4; j++)
            acc[i][j] = (float4v){0.f, 0.f, 0.f, 0.f};

    gemm_core_out(Ab, wob, smem, m0, n0, acc);

    const int tid = threadIdx.x;
    const int lane = tid & 63;
    const int l15 = lane & 15, quad = lane >> 4;
    const int wave = tid >> 6;
    const int mw = wave * 32;

    #pragma unroll
    for (int mi = 0; mi < 2; mi++) {
        #pragma unroll
        for (int r = 0; r < 4; r++) {
            const int m = m0 + mw + mi * 16 + quad * 4 + r;
            float* op = out + (size_t)m * D_MODEL + n0 + l15;
            #pragma unroll
            for (int ni = 0; ni < 4; ni++)
                op[ni * 16] = acc[mi][ni][r];
        }
    }
}

// ---------------------------------------------------------------------------
extern "C" void kernel_launch(void* const* d_in, const int* in_sizes, int n_in,
                              void* d_out, int out_size, void* d_ws, size_t ws_size,
                              hipStream_t stream)
{
    const float* x  = (const float*)d_in[0];
    const int*  pos = (const int*)d_in[1];
    const float* wq = (const float*)d_in[2];
    const float* wk = (const float*)d_in[3];
    const float* wv = (const float*)d_in[4];
    const float* wo = (const float*)d_in[5];
    float* out = (float*)d_out;

    const size_t nx = (size_t)BATCH * SEQ * D_MODEL;   // 4M
    const size_t nw = (size_t)D_MODEL * D_MODEL;       // 1M
    short* xb  = (short*)d_ws;
    short* wqb = xb + nx;
    short* wkb = wqb + nw;
    short* wvb = wkb + nw;
    short* wob = wvb + nw;
    short* Qb  = wob + nw;
    short* Kb  = Qb + nx;
    short* Vt  = Kb + nx;
    short* Ab  = Vt + nx;
    float* costab = (float*)(Ab + nx);
    float* sintab = costab + SEQ * 32;

    dim3 blk(256);
    cvt_bf16_kernel<<<dim3(2048, 6), blk, 0, stream>>>(x, wq, wk, wv, wo, pos,
                                                       xb, wqb, wkb, wvb, wob,
                                                       costab, sintab);
    qkv_mfma_kernel<<<dim3(768), blk, 0, stream>>>(xb, wqb, wkb, wvb,
                                                   costab, sintab, Qb, Kb, Vt);
    attn_mfma_kernel<<<dim3(BATCH * NUM_HEADS * (SEQ / 64)), blk, 0, stream>>>(Qb, Kb, Vt, Ab);
    out_mfma_kernel<<<dim3(512), blk, 0, stream>>>(Ab, wob, out);
}